// Round 1
// baseline (166.331 us; speedup 1.0000x reference)
//
#include <hip/hip_runtime.h>
#include <hip/hip_bf16.h>

// Fused MHA forward (B=8, I=J=1024, WIDTH=512, NH=8, HD=64), fp32 in/out.
// Strategy: cast to bf16, MFMA 16x16x32 GEMMs, fused 2-pass attention that
// writes the 268MB attn_weight output exactly once.
//
// Head mapping note: reference reshape(b, NH, i, HD) with NO transpose means
// head n = rows [n*1024,(n+1)*1024) of the per-batch (8192,64) row view.

typedef __hip_bfloat16 bf16;
typedef __attribute__((ext_vector_type(8))) short bf16x8;   // MFMA A/B frag (4 VGPR)
typedef __attribute__((ext_vector_type(4))) float f32x4;    // MFMA C/D frag

#define BATCH 8
#define SEQ   1024
#define WIDTH 512
#define NHEAD 8
#define HD    64
#define MROWS (BATCH*SEQ)                 // 8192
#define SCALE_F 0.044194173824159216f     // 512^-0.5 (width, per reference!)

static __device__ __forceinline__ unsigned short f2bf(float x) {
  union { float f; unsigned u; } a; a.f = x;
  unsigned r = a.u + 0x7fffu + ((a.u >> 16) & 1u);   // RNE
  return (unsigned short)(r >> 16);
}

static __device__ __forceinline__ void gload_lds16(const void* g, void* l) {
  // async global->LDS, 16B/lane; LDS dest = wave-uniform base + lane*16
  __builtin_amdgcn_global_load_lds((const __attribute__((address_space(1))) void*)g,
                                   (__attribute__((address_space(3))) void*)l,
                                   16, 0, 0);
}

// Swizzled LDS tile: rows of 64 bf16 (128B); 16B-unit phys col = logical ^ (row&7).
// Staging pre-applies the inverse on the GLOBAL source; reads apply it here.
static __device__ __forceinline__ bf16x8 frag_ld(const short* tile, int row, int c16) {
  int p = c16 ^ (row & 7);
  return *(const bf16x8*)(tile + row*64 + p*8);
}

// ---------------- cast fp32 -> bf16 (q,k,v + 4 weights) ----------------
__global__ void cast_all_kernel(const float* __restrict__ q, const float* __restrict__ k,
                                const float* __restrict__ v, const float* __restrict__ wq,
                                const float* __restrict__ wk, const float* __restrict__ wv,
                                const float* __restrict__ wo, bf16* __restrict__ wsb) {
  const long NQ = 1048576;   // float4 groups per q/k/v (8192*512/4)
  const long NW = 65536;     // per weight (512*512/4)
  long g = (long)blockIdx.x * blockDim.x + threadIdx.x;
  const float* src; bf16* dst; long o;
  if (g < 3*NQ) {
    int t = (int)(g / NQ); o = g - (long)t*NQ;
    src = (t==0) ? q : ((t==1) ? k : v);
    dst = wsb + (size_t)t * 4194304;
  } else {
    long g2 = g - 3*NQ;
    if (g2 >= 4*NW) return;
    int t = (int)(g2 / NW); o = g2 - (long)t*NW;
    src = (t==0) ? wq : ((t==1) ? wk : ((t==2) ? wv : wo));
    dst = wsb + (size_t)3*4194304 + (size_t)t * 262144;
  }
  float4 f = ((const float4*)src)[o];
  ushort4 r4;
  r4.x = f2bf(f.x); r4.y = f2bf(f.y); r4.z = f2bf(f.z); r4.w = f2bf(f.w);
  ((ushort4*)dst)[o] = r4;
}

// ---------------- GEMM: C[M=8192][512] = A[8192][512] @ W[512][512]^T ----------------
// 128x128 tile, BK=64, 4 waves (2x2), each wave 64x64 (4x4 16x16 frags).
template<int F32OUT>
__global__ __launch_bounds__(256) void gemm_bt(const bf16* __restrict__ A,
                                               const bf16* __restrict__ Bw,
                                               void* __restrict__ Cout) {
  __shared__ short As[128*64];
  __shared__ short Bs[128*64];
  const int lane = threadIdx.x & 63;
  const int wid  = threadIdx.x >> 6;
  const int m0 = blockIdx.x * 128;
  const int n0 = blockIdx.y * 128;
  const int wm = (wid >> 1) * 64;
  const int wn = (wid & 1) * 64;
  const int lrow = lane >> 3;                   // row-within-chunk 0..7
  const int swz  = ((lane & 7) ^ lrow) * 8;     // pre-swizzled source col (elems)

  const f32x4 zero4 = {0.f,0.f,0.f,0.f};
  f32x4 acc[4][4];
  for (int i=0;i<4;++i) for (int j=0;j<4;++j) acc[i][j] = zero4;

  for (int k0 = 0; k0 < WIDTH; k0 += 64) {
    for (int i = 0; i < 4; ++i) {
      int c = wid*4 + i;                        // 16 chunks of 1KB (8 rows each)
      int row = c*8 + lrow;
      gload_lds16(A  + (size_t)(m0 + row)*WIDTH + k0 + swz, &As[c*512]);
      gload_lds16(Bw + (size_t)(n0 + row)*WIDTH + k0 + swz, &Bs[c*512]);
    }
    asm volatile("s_waitcnt vmcnt(0)" ::: "memory");
    __syncthreads();
    for (int kc = 0; kc < 2; ++kc) {
      bf16x8 af[4], bfr[4];
      for (int mf=0; mf<4; ++mf) af[mf]  = frag_ld(As, wm + mf*16 + (lane&15), (lane>>4) + kc*4);
      for (int nf=0; nf<4; ++nf) bfr[nf] = frag_ld(Bs, wn + nf*16 + (lane&15), (lane>>4) + kc*4);
      for (int mf=0; mf<4; ++mf)
        for (int nf=0; nf<4; ++nf)
          acc[mf][nf] = __builtin_amdgcn_mfma_f32_16x16x32_bf16(af[mf], bfr[nf], acc[mf][nf], 0,0,0);
    }
    __syncthreads();
  }
  // epilogue: C row = (lane>>4)*4+r, col = lane&15 (verified layout, m89/m91)
  for (int mf=0; mf<4; ++mf)
    for (int nf=0; nf<4; ++nf) {
      int col = n0 + wn + nf*16 + (lane & 15);
      for (int r=0; r<4; ++r) {
        int row = m0 + wm + mf*16 + (lane>>4)*4 + r;
        if (F32OUT)
          ((float*)Cout)[(size_t)row*WIDTH + col] = acc[mf][nf][r];
        else
          ((unsigned short*)Cout)[(size_t)row*WIDTH + col] = f2bf(acc[mf][nf][r]);
      }
    }
}

// ---------------- V transpose: per head (1024,64) -> (64,1024) ----------------
__global__ __launch_bounds__(256) void transpose_v(const bf16* __restrict__ Vh,
                                                   bf16* __restrict__ Vt) {
  __shared__ short t[64][72];                   // +8 pad breaks bank conflicts
  int h  = blockIdx.x >> 4;
  int j0 = (blockIdx.x & 15) * 64;
  const bf16* src = Vh + (size_t)h * (SEQ*HD);
  bf16* dst = Vt + (size_t)h * (SEQ*HD);
  int tid = threadIdx.x;
  int r  = tid >> 2;                            // 0..63
  int c0 = (tid & 3) * 16;                      // 0,16,32,48
  bf16x8 v0 = *(const bf16x8*)(src + (size_t)(j0 + r)*HD + c0);
  bf16x8 v1 = *(const bf16x8*)(src + (size_t)(j0 + r)*HD + c0 + 8);
  for (int i = 0; i < 8; ++i) { t[r][c0+i] = v0[i]; t[r][c0+8+i] = v1[i]; }
  __syncthreads();
  bf16x8 w0, w1;
  for (int i = 0; i < 8; ++i) { w0[i] = t[c0+i][r]; w1[i] = t[c0+8+i][r]; }
  *(bf16x8*)(dst + (size_t)r*SEQ + j0 + c0)     = w0;
  *(bf16x8*)(dst + (size_t)r*SEQ + j0 + c0 + 8) = w1;
}

// ---------------- fused attention ----------------
// Block = 4 waves x 16 rows = 64 q-rows of one head. Pass A: row sum of exp.
// Pass B: recompute S, write normalized weights (268MB, once), PV accumulate.
__global__ __launch_bounds__(256) void attn_kernel(const bf16* __restrict__ Qh,
                                                   const bf16* __restrict__ Kh,
                                                   const bf16* __restrict__ Vt,
                                                   float* __restrict__ attn_out,
                                                   bf16* __restrict__ ctx) {
  __shared__ short Ks[64*64];        // [j][d] swizzled
  __shared__ short Vs[64*64];        // [d][j] swizzled (from Vt)
  __shared__ short Ws[4][16*64];     // per-wave P tile [i][j] swizzled

  const int lane = threadIdx.x & 63;
  const int wid  = threadIdx.x >> 6;
  const int h  = blockIdx.x >> 4;            // b*8+n
  const int i0 = (blockIdx.x & 15) * 64;
  const int b  = h >> 3;
  const int nh = h & 7;

  const bf16* Qhead  = Qh + (size_t)h * (SEQ*HD);
  const bf16* Khead  = Kh + (size_t)h * (SEQ*HD);
  const bf16* Vthead = Vt + (size_t)h * (SEQ*HD);

  const int lrow = lane >> 3;
  const int swz  = ((lane & 7) ^ lrow) * 8;

  // Q fragments (16 rows per wave, K-dim 64 = 2 chunks of 32), direct from global
  const int qrow = i0 + wid*16 + (lane & 15);
  bf16x8 qf[2];
  qf[0] = *(const bf16x8*)(Qhead + (size_t)qrow*HD + (lane>>4)*8);
  qf[1] = *(const bf16x8*)(Qhead + (size_t)qrow*HD + 32 + (lane>>4)*8);

  const f32x4 zero4 = {0.f,0.f,0.f,0.f};

  // ---- pass A: l_i = sum_j exp(S_ij * scale)  (|S*scale| ~< 3, no max needed) ----
  float lsum[4] = {0.f,0.f,0.f,0.f};
  for (int jt = 0; jt < 16; ++jt) {
    const int j0 = jt * 64;
    for (int i = 0; i < 2; ++i) {
      int c = wid*2 + i;
      gload_lds16(Khead + (size_t)(j0 + c*8 + lrow)*HD + swz, &Ks[c*512]);
    }
    asm volatile("s_waitcnt vmcnt(0)" ::: "memory");
    __syncthreads();
    f32x4 sac[4] = {zero4, zero4, zero4, zero4};
    for (int kc = 0; kc < 2; ++kc)
      for (int jf = 0; jf < 4; ++jf) {
        bf16x8 kf = frag_ld(Ks, jf*16 + (lane & 15), (lane>>4) + kc*4);
        sac[jf] = __builtin_amdgcn_mfma_f32_16x16x32_bf16(qf[kc], kf, sac[jf], 0, 0, 0);
      }
    for (int jf = 0; jf < 4; ++jf)
      for (int r = 0; r < 4; ++r)
        lsum[r] += __expf(sac[jf][r] * SCALE_F);
    __syncthreads();
  }
  // reduce across the 16 lanes holding different j-cols of the same rows
  for (int m = 1; m < 16; m <<= 1)
    for (int r = 0; r < 4; ++r)
      lsum[r] += __shfl_xor(lsum[r], m, 64);
  float linv[4];
  for (int r = 0; r < 4; ++r) linv[r] = 1.0f / lsum[r];

  // ---- pass B: recompute S, emit weights, PV ----
  f32x4 cacc[4] = {zero4, zero4, zero4, zero4};
  short* Wsw = &Ws[wid][0];
  for (int jt = 0; jt < 16; ++jt) {
    const int j0 = jt * 64;
    for (int i = 0; i < 2; ++i) {
      int c = wid*2 + i;
      gload_lds16(Khead  + (size_t)(j0 + c*8 + lrow)*HD + swz,  &Ks[c*512]);
      gload_lds16(Vthead + (size_t)(c*8 + lrow)*SEQ + j0 + swz, &Vs[c*512]);
    }
    asm volatile("s_waitcnt vmcnt(0)" ::: "memory");
    __syncthreads();
    f32x4 sac[4] = {zero4, zero4, zero4, zero4};
    for (int kc = 0; kc < 2; ++kc)
      for (int jf = 0; jf < 4; ++jf) {
        bf16x8 kf = frag_ld(Ks, jf*16 + (lane & 15), (lane>>4) + kc*4);
        sac[jf] = __builtin_amdgcn_mfma_f32_16x16x32_bf16(qf[kc], kf, sac[jf], 0, 0, 0);
      }
    // normalize, write attn_weight (fp32, coalesced 64B/16-lane group), stash bf16 P
    for (int jf = 0; jf < 4; ++jf)
      for (int r = 0; r < 4; ++r) {
        float w = __expf(sac[jf][r] * SCALE_F) * linv[r];
        int row = (lane>>4)*4 + r;
        int col = jf*16 + (lane & 15);
        attn_out[(size_t)(h*SEQ + i0 + wid*16 + row)*SEQ + j0 + col] = w;
        Wsw[row*64 + (((col>>3) ^ (row & 7))<<3) + (col & 7)] = (short)f2bf(w);
      }
    asm volatile("s_waitcnt lgkmcnt(0)" ::: "memory");  // cross-lane LDS visibility (same wave)
    for (int kc = 0; kc < 2; ++kc) {
      bf16x8 wa = frag_ld(Wsw, lane & 15, (lane>>4) + kc*4);
      for (int df = 0; df < 4; ++df) {
        bf16x8 vb = frag_ld(Vs, df*16 + (lane & 15), (lane>>4) + kc*4);
        cacc[df] = __builtin_amdgcn_mfma_f32_16x16x32_bf16(wa, vb, cacc[df], 0, 0, 0);
      }
    }
    __syncthreads();
  }
  // ctx[b][i'][nh*64+d]  (the transpose(0,2,1,3) happens here)
  for (int df = 0; df < 4; ++df)
    for (int r = 0; r < 4; ++r) {
      int irow = i0 + wid*16 + (lane>>4)*4 + r;
      ((unsigned short*)ctx)[(size_t)(b*SEQ + irow)*WIDTH + nh*HD + df*16 + (lane & 15)]
          = f2bf(cacc[df][r]);
    }
}

// ---------------- launcher ----------------
extern "C" void kernel_launch(void* const* d_in, const int* in_sizes, int n_in,
                              void* d_out, int out_size, void* d_ws, size_t ws_size,
                              hipStream_t stream) {
  const float* q  = (const float*)d_in[0];
  const float* k  = (const float*)d_in[1];
  const float* v  = (const float*)d_in[2];
  const float* wq = (const float*)d_in[3];
  const float* wk = (const float*)d_in[4];
  const float* wv = (const float*)d_in[5];
  const float* wo = (const float*)d_in[6];

  bf16* wsb = (bf16*)d_ws;              // workspace layout (bf16 elems):
  bf16* qb  = wsb;                      // q,k,v casts: 3 x 4194304
  bf16* kb  = qb + 4194304;
  bf16* vb  = kb + 4194304;
  bf16* wqb = vb + 4194304;             // weights: 4 x 262144
  bf16* wkb = wqb + 262144;
  bf16* wvb = wkb + 262144;
  bf16* wob = wvb + 262144;
  bf16* Qh  = wob + 262144;             // projections: 4194304 each
  bf16* Kh  = Qh + 4194304;
  bf16* Vh  = Kh + 4194304;
  bf16* Vt  = Vh + 4194304;             // per-head transposed V
  bf16* ctx = Vt + 4194304;             // pre-Wo context (total ws ~66 MB)

  float* x_out    = (float*)d_out;             // (8,1024,512)
  float* attn_out = (float*)d_out + 4194304;   // (8,8,1024,1024)

  cast_all_kernel<<<13312, 256, 0, stream>>>(q, k, v, wq, wk, wv, wo, wsb);
  gemm_bt<0><<<dim3(64,4), 256, 0, stream>>>(qb, wqb, (void*)Qh);
  gemm_bt<0><<<dim3(64,4), 256, 0, stream>>>(kb, wkb, (void*)Kh);
  gemm_bt<0><<<dim3(64,4), 256, 0, stream>>>(vb, wvb, (void*)Vh);
  transpose_v<<<1024, 256, 0, stream>>>(Vh, Vt);
  attn_kernel<<<1024, 256, 0, stream>>>(Qh, Kh, Vt, attn_out, ctx);
  gemm_bt<1><<<dim3(64,4), 256, 0, stream>>>(ctx, wob, (void*)x_out);
}